// Round 7
// baseline (2945.869 us; speedup 1.0000x reference)
//
#include <hip/hip_runtime.h>
#include <hip/hip_bf16.h>

#define MDIM 4096
#define DDIM 2048
#define HDIM 2048
#define EDIM 8
#define HD   ((size_t)HDIM * DDIM)

typedef float v4f __attribute__((ext_vector_type(4)));
typedef int   v4i __attribute__((ext_vector_type(4)));
typedef int   v8i __attribute__((ext_vector_type(8)));

// async global->LDS, 16B per lane. lds pointer must be wave-uniform
// (HW writes base + lane*16).
__device__ __forceinline__ void gl2lds16(const void* g, void* l) {
  __builtin_amdgcn_global_load_lds(
      (const __attribute__((address_space(1))) void*)g,
      (__attribute__((address_space(3))) void*)l,
      16, 0, 0);
}

// ---------------- Kernel 1: gating softmax + fp8 quantize of x ----------------
__global__ __launch_bounds__(256) void k_gate_xq(
    const float* __restrict__ x, const float* __restrict__ gw,
    const float* __restrict__ gb, float* __restrict__ gate,
    unsigned char* __restrict__ x8)
{
  const int wid  = threadIdx.x >> 6;
  const int lane = threadIdx.x & 63;
  const int m    = blockIdx.x * 4 + wid;

  const float4* xr = (const float4*)(x + (size_t)m * DDIM);
  unsigned int* qr = (unsigned int*)(x8 + (size_t)m * DDIM);

  float part[EDIM];
#pragma unroll
  for (int e = 0; e < EDIM; ++e) part[e] = 0.f;

#pragma unroll
  for (int it = 0; it < DDIM / 4 / 64; ++it) {   // 8 iterations
    const int idx = it * 64 + lane;
    const float4 xv = xr[idx];
    int pk = __builtin_amdgcn_cvt_pk_fp8_f32(xv.x, xv.y, 0, false);
    pk = __builtin_amdgcn_cvt_pk_fp8_f32(xv.z, xv.w, pk, true);
    qr[idx] = (unsigned int)pk;
#pragma unroll
    for (int e = 0; e < EDIM; ++e) {
      const float4 wv = ((const float4*)(gw + (size_t)e * DDIM))[idx];
      part[e] += xv.x * wv.x + xv.y * wv.y + xv.z * wv.z + xv.w * wv.w;
    }
  }
#pragma unroll
  for (int e = 0; e < EDIM; ++e) {
#pragma unroll
    for (int off = 32; off > 0; off >>= 1)
      part[e] += __shfl_xor(part[e], off);
  }
  float lg[EDIM];
  float s = 0.f;
#pragma unroll
  for (int e = 0; e < EDIM; ++e) lg[e] = part[e] + gb[e];
  float mx = lg[0];
#pragma unroll
  for (int e = 1; e < EDIM; ++e) mx = fmaxf(mx, lg[e]);
#pragma unroll
  for (int e = 0; e < EDIM; ++e) { lg[e] = expf(lg[e] - mx); s += lg[e]; }
  const float inv = 1.f / s;
  if (lane < EDIM) gate[m * EDIM + lane] = lg[lane] * inv;
}

// ---------------- Kernel 2: fp8 quantize of expert_w --------------------------
__global__ void k_wq(const float* __restrict__ w, unsigned char* __restrict__ w8)
{
  const long long n4 = (long long)EDIM * HDIM * DDIM / 4;
  const long long stride = (long long)gridDim.x * blockDim.x;
  for (long long i = (long long)blockIdx.x * blockDim.x + threadIdx.x; i < n4;
       i += stride) {
    const float4 v = ((const float4*)w)[i];
    int pk = __builtin_amdgcn_cvt_pk_fp8_f32(v.x, v.y, 0, false);
    pk = __builtin_amdgcn_cvt_pk_fp8_f32(v.z, v.w, pk, true);
    ((unsigned int*)w8)[i] = (unsigned int)pk;
  }
}

// ---------------- Kernel 3: fused grouped GEMM + gated combine ----------------
// 512 threads (8 waves, 4m x 2n), tile 256x128, per-wave 64x64, BK=128.
// LOOP INVERSION: outer k-tile (16), inner expert (8). A-fragments are read
// from LDS to registers ONCE per k-tile and reused for all 8 experts' B-tiles
// (gate folded per k-tile: outacc += g_e * mfma(A, B_e, 0); bf16-round skip
// bounded ~2^-9*|y|, validated in R5/R6 absmax). LDS read traffic per step
// drops from 128KB to ~72KB per CU -> MFMA/LDS balanced instead of LDS-bound.
// Registers: outacc 64 + av 32 + working ~70 (no spill; R6's 128-reg outacc
// spilled 2.9GB to scratch).
// LDS: A dbuf 2x32KB (restaged once per 8 steps) + B pingpong 2x16KB (every
// step) + gate f32 cache 8KB = 104KB. T2 both-sides XOR swizzle unchanged.
// Counted vmcnt with in-order completion semantics: A-prefetch issued FIRST
// in the kt (so it is older than any B it would block): waits 6,6,2,2,2,2,2,2.
__global__ __launch_bounds__(512, 2) void k_moe_gemm(
    const unsigned char* __restrict__ x8,   // [M, D]
    const unsigned char* __restrict__ w8,   // [E, H, D]
    const float* __restrict__ gate,         // [M, 8]
    float* __restrict__ out)                // [M, H] f32
{
  extern __shared__ unsigned char smem[];   // 65536 A + 32768 B + 8192 G

  const int tid  = threadIdx.x;
  const int lane = tid & 63;
  const int wid  = tid >> 6;
  const int wm   = wid >> 1;        // 0..3  (64-row group)
  const int wn   = wid & 1;         // 0..1  (64-col group)

  // XCD chunking: 256 blocks; each XCD owns a 4x8 square of (m,h) tiles.
  const int bid   = blockIdx.x;
  const int xcd   = bid & 7;
  const int local = bid >> 3;                        // 0..31
  const int tm    = (xcd >> 1) * 4 + (local >> 3);   // 0..15
  const int tn    = (xcd & 1) * 8 + (local & 7);     // 0..15
  const int bm    = tm * 256;
  const int bn    = tn * 128;

  const int lrow = lane & 15;
  const int lk   = lane >> 4;             // 0..3 -> k-block of 32 bytes
  const int swz  = (lrow & 7) << 4;
  const int c0   = (lk * 32) ^ swz;       // swizzled 16B chunk cols
  const int c1   = c0 ^ 16;

  float* sGf = (float*)(smem + 98304);    // [8 experts][256 rows] f32

  // staging source coords: thread covers row strow (of a 64-row slab),
  // inverse-swizzled col stcol; each gl2lds16 stages one 64x128 slab chunk.
  const int strow = tid >> 3;
  const int stcol = ((tid & 7) * 16) ^ ((strow & 7) << 4);
  const unsigned char* abase0 = x8 + (size_t)(bm +   0 + strow) * DDIM + stcol;
  const unsigned char* abase1 = x8 + (size_t)(bm +  64 + strow) * DDIM + stcol;
  const unsigned char* abase2 = x8 + (size_t)(bm + 128 + strow) * DDIM + stcol;
  const unsigned char* abase3 = x8 + (size_t)(bm + 192 + strow) * DDIM + stcol;
  const unsigned char* bbase0 = w8 + (size_t)(bn +   0 + strow) * DDIM + stcol;
  const unsigned char* bbase1 = w8 + (size_t)(bn +  64 + strow) * DDIM + stcol;

  v4f outacc[4][4];
#pragma unroll
  for (int i = 0; i < 4; ++i)
#pragma unroll
    for (int j = 0; j < 4; ++j) {
      outacc[i][j][0] = 0.f; outacc[i][j][1] = 0.f;
      outacc[i][j][2] = 0.f; outacc[i][j][3] = 0.f;
    }
  v8i av[4];
  const v4f zero4 = {0.f, 0.f, 0.f, 0.f};

// stage A k-tile KT into abuf[KT&1] (4 x 8KB slabs, 4 loads/thread)
#define STAGE_A(KT) do {                                                       \
    const size_t k_ = (size_t)(KT) * 128;                                      \
    unsigned char* d_ = smem + ((KT) & 1) * 32768 + wid * 1024;                \
    gl2lds16(abase0 + k_, (void*)d_);                                          \
    gl2lds16(abase1 + k_, (void*)(d_ + 8192));                                 \
    gl2lds16(abase2 + k_, (void*)(d_ + 16384));                                \
    gl2lds16(abase3 + k_, (void*)(d_ + 24576));                                \
  } while (0)

// stage B tile for global step S (= kt*8 + e) into bbuf[S&1] (2 loads/thread)
#define STAGE_B(S) do {                                                        \
    const size_t off_ = (size_t)((S) & 7) * HD + (size_t)((S) >> 3) * 128;     \
    unsigned char* d_ = smem + 65536 + ((S) & 1) * 16384 + wid * 1024;         \
    gl2lds16(bbase0 + off_, (void*)d_);                                        \
    gl2lds16(bbase1 + off_, (void*)(d_ + 8192));                               \
  } while (0)

// A-fragments LDS -> registers (once per k-tile)
#define LOADA(KT) do {                                                         \
    const unsigned char* pA_ = smem + ((KT) & 1) * 32768 +                     \
                               (size_t)(wm * 64 + lrow) * 128;                 \
    _Pragma("unroll") for (int f = 0; f < 4; ++f) {                            \
      union { v8i v; v4i h[2]; } u_;                                           \
      u_.h[0] = *(const v4i*)(pA_ + f * 2048 + c0);                            \
      u_.h[1] = *(const v4i*)(pA_ + f * 2048 + c1);                            \
      av[f] = u_.v;                                                            \
    }                                                                          \
  } while (0)

#define COMP(KT, E) do {                                                       \
    v4f g4_[4];                                                                \
    _Pragma("unroll") for (int i = 0; i < 4; ++i)                              \
      g4_[i] = *(const v4f*)(sGf + (E) * 256 + wm * 64 + i * 16 + lk * 4);     \
    const unsigned char* pB_ = smem + 65536 + ((E) & 1) * 16384 +              \
                               (size_t)(wn * 64 + lrow) * 128;                 \
    __builtin_amdgcn_s_setprio(1);                                             \
    _Pragma("unroll") for (int j = 0; j < 4; ++j) {                            \
      union { v8i v; v4i h[2]; } u_;                                           \
      u_.h[0] = *(const v4i*)(pB_ + j * 2048 + c0);                            \
      u_.h[1] = *(const v4i*)(pB_ + j * 2048 + c1);                            \
      const v8i bv_ = u_.v;                                                    \
      _Pragma("unroll") for (int i = 0; i < 4; ++i) {                          \
        const v4f t_ = __builtin_amdgcn_mfma_scale_f32_16x16x128_f8f6f4(       \
            av[i], bv_, zero4, 0 /*fp8*/, 0 /*fp8*/,                           \
            0, 127 /*e8m0 1.0*/, 0, 127 /*e8m0 1.0*/);                         \
        outacc[i][j][0] += g4_[i][0] * t_[0];                                  \
        outacc[i][j][1] += g4_[i][1] * t_[1];                                  \
        outacc[i][j][2] += g4_[i][2] * t_[2];                                  \
        outacc[i][j][3] += g4_[i][3] * t_[3];                                  \
      }                                                                        \
    }                                                                          \
    __builtin_amdgcn_s_setprio(0);                                             \
  } while (0)

#define STEP(KT, E, WAIT, DOB, DOA) do {                                       \
    if (DOB) STAGE_B((KT) * 8 + (E) + 1);                                      \
    if (DOA) STAGE_A((KT) + 1);                                                \
    asm volatile("s_waitcnt vmcnt(" #WAIT ")" ::: "memory");                   \
    __builtin_amdgcn_s_barrier();                                              \
    __builtin_amdgcn_sched_barrier(0);                                         \
    if ((E) == 0) LOADA(KT);                                                   \
    COMP((KT), (E));                                                           \
    __builtin_amdgcn_sched_barrier(0);                                         \
    __builtin_amdgcn_s_barrier();                                              \
  } while (0)

  // ---- prologue: gate cache (f32, [e][256]) + stage A0, B(0,0)
  {
    const int e = tid >> 6, grp = tid & 63;
    float4 gv;
    gv.x = gate[(size_t)(bm + 4 * grp + 0) * EDIM + e];
    gv.y = gate[(size_t)(bm + 4 * grp + 1) * EDIM + e];
    gv.z = gate[(size_t)(bm + 4 * grp + 2) * EDIM + e];
    gv.w = gate[(size_t)(bm + 4 * grp + 3) * EDIM + e];
    *(float4*)(sGf + e * 256 + 4 * grp) = gv;
  }
  STAGE_A(0);
  STAGE_B(0);
  __syncthreads();   // drains prologue loads + publishes sGf (once)

  // ---- main loop: kt outer (A reused across experts), e inner
  for (int kt = 0; kt < 15; ++kt) {
    STEP(kt, 0, 6, 1, 1);   // issues B(kt,1) + A(kt+1); needs A(kt),B(kt,0)
    STEP(kt, 1, 6, 1, 0);   // allow A'(4)+B2(2) in flight
    STEP(kt, 2, 2, 1, 0);   // from here only B-next may be in flight
    STEP(kt, 3, 2, 1, 0);
    STEP(kt, 4, 2, 1, 0);
    STEP(kt, 5, 2, 1, 0);
    STEP(kt, 6, 2, 1, 0);
    STEP(kt, 7, 2, 1, 0);   // stages B(kt+1, 0)
  }
  // kt = 15: no A prefetch
  STEP(15, 0, 2, 1, 0);
  STEP(15, 1, 2, 1, 0);
  STEP(15, 2, 2, 1, 0);
  STEP(15, 3, 2, 1, 0);
  STEP(15, 4, 2, 1, 0);
  STEP(15, 5, 2, 1, 0);
  STEP(15, 6, 2, 1, 0);
  STEP(15, 7, 0, 0, 0);

#undef STEP
#undef COMP
#undef LOADA
#undef STAGE_B
#undef STAGE_A

  // epilogue: direct coalesced stores (single block per output tile)
#pragma unroll
  for (int i = 0; i < 4; ++i)
#pragma unroll
    for (int q = 0; q < 4; ++q) {
      const size_t r = (size_t)(bm + wm * 64 + i * 16 + lk * 4 + q);
      float* orow = out + r * HDIM + bn + wn * 64 + lrow;
#pragma unroll
      for (int j = 0; j < 4; ++j)
        orow[j * 16] = outacc[i][j][q];
    }
}

extern "C" void kernel_launch(void* const* d_in, const int* in_sizes, int n_in,
                              void* d_out, int out_size, void* d_ws, size_t ws_size,
                              hipStream_t stream) {
  (void)in_sizes; (void)n_in; (void)out_size; (void)ws_size;
  const float* x        = (const float*)d_in[0];
  const float* gate_w   = (const float*)d_in[1];
  const float* gate_b   = (const float*)d_in[2];
  const float* expert_w = (const float*)d_in[3];
  float* out = (float*)d_out;

  char* ws = (char*)d_ws;
  float* gate       = (float*)ws;                                   // 131072 B
  unsigned char* x8 = (unsigned char*)(ws + 131072);                // 8 MiB
  unsigned char* w8 = (unsigned char*)(ws + 131072 + (size_t)MDIM * DDIM);

  hipLaunchKernelGGL(k_gate_xq, dim3(MDIM / 4), dim3(256), 0, stream,
                     x, gate_w, gate_b, gate, x8);
  hipLaunchKernelGGL(k_wq, dim3(4096), dim3(256), 0, stream, expert_w, w8);
  hipLaunchKernelGGL(k_moe_gemm, dim3(256), dim3(512), 106496, stream,
                     x8, w8, gate, out);
}